// Round 5
// baseline (178.636 us; speedup 1.0000x reference)
//
#include <hip/hip_runtime.h>

#define B_SZ 2
#define T_SZ 2048
#define DM   1024
#define NH   16
#define DH   64

typedef __attribute__((ext_vector_type(8))) short bf16x8;
typedef __attribute__((ext_vector_type(4))) float f32x4;
typedef __attribute__((ext_vector_type(4))) unsigned int u32x4;
typedef __attribute__((ext_vector_type(4))) unsigned short u16x4;

__device__ __forceinline__ unsigned short f2bf(float f) {
  unsigned u = __builtin_bit_cast(unsigned, f);
  u += 0x7FFFu + ((u >> 16) & 1u);
  return (unsigned short)(u >> 16);
}
__device__ __forceinline__ unsigned packbf(float lo, float hi) {
  return (unsigned)f2bf(lo) | ((unsigned)f2bf(hi) << 16);
}

// stage 16 f32 -> 16 bf16 into LDS
__device__ __forceinline__ void stage16(const float* src, unsigned short* dst) {
  const f32x4* ps = (const f32x4*)src;
  f32x4 v0 = ps[0], v1 = ps[1], v2 = ps[2], v3 = ps[3];
  u32x4 w0, w1;
  w0[0] = packbf(v0[0], v0[1]); w0[1] = packbf(v0[2], v0[3]);
  w0[2] = packbf(v1[0], v1[1]); w0[3] = packbf(v1[2], v1[3]);
  w1[0] = packbf(v2[0], v2[1]); w1[1] = packbf(v2[2], v2[3]);
  w1[2] = packbf(v3[0], v3[1]); w1[3] = packbf(v3[2], v3[3]);
  *(u32x4*)dst = w0;
  *(u32x4*)(dst + 8) = w1;
}

// async global->LDS, 16B per lane
__device__ __forceinline__ void gload16(const unsigned short* g, unsigned short* l) {
  __builtin_amdgcn_global_load_lds(
      (const __attribute__((address_space(1))) unsigned int*)(const void*)g,
      (__attribute__((address_space(3))) unsigned int*)(void*)l, 16, 0, 0);
}

__device__ __forceinline__ void cvt16(const float* s, unsigned short* d, float scale) {
  const f32x4* ps = (const f32x4*)s;
  f32x4 v0 = ps[0] * scale, v1 = ps[1] * scale, v2 = ps[2] * scale, v3 = ps[3] * scale;
  u32x4 w0, w1;
  w0[0] = packbf(v0[0], v0[1]); w0[1] = packbf(v0[2], v0[3]);
  w0[2] = packbf(v1[0], v1[1]); w0[3] = packbf(v1[2], v1[3]);
  w1[0] = packbf(v2[0], v2[1]); w1[1] = packbf(v2[2], v2[3]);
  w1[2] = packbf(v3[0], v3[1]); w1[3] = packbf(v3[2], v3[3]);
  *(u32x4*)d = w0;
  *(u32x4*)(d + 8) = w1;
}

// 4 weight tensors in one launch (y selects); y==0 gets qscale
__global__ __launch_bounds__(256) void cvt_w4(
    const float* __restrict__ s0, const float* __restrict__ s1,
    const float* __restrict__ s2, const float* __restrict__ s3,
    unsigned short* __restrict__ d0, unsigned short* __restrict__ d1,
    unsigned short* __restrict__ d2, unsigned short* __restrict__ d3,
    float qscale) {
  const int y = blockIdx.y;
  const float* s = (y == 0) ? s0 : (y == 1) ? s1 : (y == 2) ? s2 : s3;
  unsigned short* d = (y == 0) ? d0 : (y == 1) ? d1 : (y == 2) ? d2 : d3;
  const float sc = (y == 0) ? qscale : 1.0f;
  const int i = (blockIdx.x * 256 + threadIdx.x) * 16;
  cvt16(s + i, d + i, sc);
}

// q_raw & kv_raw in one launch
__global__ __launch_bounds__(256) void cvt_in2(
    const float* __restrict__ s0, const float* __restrict__ s1,
    unsigned short* __restrict__ d0, unsigned short* __restrict__ d1) {
  const int y = blockIdx.y;
  const float* s = y ? s1 : s0;
  unsigned short* d = y ? d1 : d0;
  const int i = (blockIdx.x * 256 + threadIdx.x) * 16;
  cvt16(s + i, d + i, 1.0f);
}

// C = A * B^T, tile 128x64, BK=32, MFMA 16x16x32 bf16.  (unchanged from R4)
template<int AMODE, int BMODE, int CMODE>
__global__ __launch_bounds__(256) void gemm2(
    const void* __restrict__ A0, const void* __restrict__ A1, int lda,
    const void* __restrict__ B0, const void* __restrict__ B1, int ldb, long bZ,
    void* __restrict__ C0, void* __restrict__ C1, int K) {
  __shared__ unsigned short As[128 * 32];
  __shared__ unsigned short Bs[64 * 32];
  const int tid = threadIdx.x, lane = tid & 63, w = tid >> 6;
  const int wm = w >> 1, wn = w & 1;
  const int l15 = lane & 15, lg = lane >> 4;
  const int mblk = blockIdx.y * 128, nblk = blockIdx.x * 64;
  const int z = blockIdx.z;

  const void* Ap; const void* Bp; void* Cp;
  long aoff = 0; int zb = 0, zs = 0;
  if constexpr (CMODE == 0) {
    Ap = z ? A1 : A0; Bp = z ? B1 : B0; Cp = z ? C1 : C0;
  } else if constexpr (CMODE == 2) {
    Ap = A0; Cp = C0;
    if constexpr (BMODE == 1) Bp = (const void*)((const unsigned short*)B0 + (long)z * bZ);
    else                      Bp = (const void*)((const float*)B0 + (long)z * bZ);
  } else {
    Ap = A0; Bp = B0; Cp = C0;
    zb = z >> 1; zs = z & 1;
    aoff = (long)zb * 2097152 + (long)zs * 1024;
  }

  f32x4 acc[4][2];
#pragma unroll
  for (int i = 0; i < 4; i++)
#pragma unroll
    for (int j = 0; j < 2; j++) acc[i][j] = (f32x4){0.f, 0.f, 0.f, 0.f};

  const int asr = tid >> 1, asc = (tid & 1) * 16;
  const int agr = w * 32 + (lane >> 2), agc = (lane & 3) * 8;
  const int bgr = w * 16 + (lane >> 2), bgc = (lane & 3) * 8;

  for (int k0 = 0; k0 < K; k0 += 32) {
    if constexpr (AMODE == 0) {
      stage16((const float*)Ap + (long)(mblk + asr) * lda + k0 + asc, &As[asr * 32 + asc]);
    } else {
      const unsigned short* Ab = (const unsigned short*)Ap + aoff;
      gload16(Ab + (long)(mblk + agr) * lda + k0 + agc, &As[w * 1024]);
      gload16(Ab + (long)(mblk + agr + 16) * lda + k0 + agc, &As[w * 1024 + 512]);
    }
    if constexpr (BMODE == 0) {
      if (tid < 128)
        stage16((const float*)Bp + (long)(nblk + asr) * ldb + k0 + asc, &Bs[asr * 32 + asc]);
    } else {
      gload16((const unsigned short*)Bp + (long)(nblk + bgr) * ldb + k0 + bgc, &Bs[w * 512]);
    }
    __syncthreads();

    bf16x8 af[4], bfr[2];
#pragma unroll
    for (int mi = 0; mi < 4; mi++)
      af[mi] = *(const bf16x8*)&As[(wm * 64 + mi * 16 + l15) * 32 + lg * 8];
#pragma unroll
    for (int nj = 0; nj < 2; nj++)
      bfr[nj] = *(const bf16x8*)&Bs[(wn * 32 + nj * 16 + l15) * 32 + lg * 8];
#pragma unroll
    for (int mi = 0; mi < 4; mi++)
#pragma unroll
      for (int nj = 0; nj < 2; nj++)
        acc[mi][nj] = __builtin_amdgcn_mfma_f32_16x16x32_bf16(af[mi], bfr[nj], acc[mi][nj], 0, 0, 0);
    __syncthreads();
  }

#pragma unroll
  for (int mi = 0; mi < 4; mi++) {
#pragma unroll
    for (int nj = 0; nj < 2; nj++) {
#pragma unroll
      for (int r = 0; r < 4; r++) {
        const int i = mblk + wm * 64 + mi * 16 + lg * 4 + r;
        const int n = nblk + wn * 32 + nj * 16 + l15;
        const float v = acc[mi][nj][r];
        if constexpr (CMODE == 0) {
          const int b = i >> 11, t = i & 2047, h = n >> 6, d = n & 63;
          ((unsigned short*)Cp)[((long)(b * NH + h) * T_SZ + t) * DH + d] = f2bf(v);
        } else if constexpr (CMODE == 2) {
          ((unsigned short*)Cp)[(long)z * 2097152 + (long)i * 2048 + n] = f2bf(v);
        } else {
          ((float*)Cp)[(long)zb * T_SZ * DM + (long)(2 * i + zs) * DM + n] = v;
        }
      }
    }
  }
}

// Flash attention, causal + kv padding mask. Single 64-row q-tile per block,
// grid 1024 (4 blocks/CU), descending-work dispatch order, exp2-domain softmax.
// Qh/Kh: [b*16+h][t][d] bf16 (Q pre-scaled log2e/8). Vt/Zt: [b][c][t] bf16.
__global__ __launch_bounds__(256) void attn_kernel(const unsigned short* __restrict__ Qh,
                                                   const unsigned short* __restrict__ Kh,
                                                   const unsigned short* __restrict__ Vt,
                                                   const int* __restrict__ kmask,
                                                   unsigned short* __restrict__ Zt) {
  __shared__ unsigned short lds_k[64][72];
  __shared__ unsigned short lds_vt[64][72];
  __shared__ unsigned short lds_p[4][16][72];
  const int tid = threadIdx.x, lane = tid & 63, w = tid >> 6;
  const int l15 = lane & 15, lg = lane >> 4;
  // XCD-aware decode: 4 bh per XCD; within an XCD, big tiles dispatch first.
  const int wg = blockIdx.x;
  const int xcd = wg & 7, lin = wg >> 3;       // lin in 0..127
  const int bh = xcd * 4 + (lin >> 5);
  const int p = 31 - (lin & 31);               // descending work
  const int b = bh >> 4;
  const int h = bh & 15;
  const int q0 = p * 64;
  const unsigned short* Qb = Qh + ((long)bh << 17);
  const unsigned short* Kb = Kh + ((long)bh << 17);
  const unsigned short* Vtb = Vt + ((long)(b * DM + h * DH)) * T_SZ;

  const int qra = q0 + w * 16 + l15;
  bf16x8 qf0 = *(const bf16x8*)(Qb + ((long)qra << 6) + lg * 8);
  bf16x8 qf1 = *(const bf16x8*)(Qb + ((long)qra << 6) + 32 + lg * 8);

  f32x4 o[4];
  float mr[4], lr[4];
#pragma unroll
  for (int i = 0; i < 4; i++) {
    o[i] = (f32x4){0.f, 0.f, 0.f, 0.f};
    mr[i] = -1e30f; lr[i] = 0.f;
  }

  const int sr = tid >> 2, sc = (tid & 3) * 16;
  const unsigned short* kp = Kb + ((long)sr << 6) + sc;
  const unsigned short* vp = Vtb + (long)sr * T_SZ + sc;
  const int mbase = b * T_SZ + lane;
  const int qc0 = q0 + w * 16 + lg * 4;

  u32x4 rk0, rk1, rv0, rv1;
  int rmk;
  auto issue = [&](int j0) {
    const u32x4* ks = (const u32x4*)(kp + ((long)j0 << 6));
    rk0 = ks[0]; rk1 = ks[1];
    const u32x4* vs = (const u32x4*)(vp + j0);
    rv0 = vs[0]; rv1 = vs[1];
    rmk = kmask[mbase + j0];
  };

  issue(0);
  for (int j0 = 0; j0 <= q0; j0 += 64) {
    __syncthreads();
    *(u32x4*)&lds_k[sr][sc] = rk0;  *(u32x4*)&lds_k[sr][sc + 8] = rk1;
    *(u32x4*)&lds_vt[sr][sc] = rv0; *(u32x4*)&lds_vt[sr][sc + 8] = rv1;
    const unsigned long long kvm = __ballot(rmk != 0);
    __syncthreads();
    if (j0 + 64 <= q0) issue(j0 + 64);

    // S = Q K^T (scores already in log2 domain via Q pre-scale)
    f32x4 sa[4];
    __builtin_amdgcn_s_setprio(1);
#pragma unroll
    for (int cb = 0; cb < 4; cb++) {
      bf16x8 kf0 = *(const bf16x8*)&lds_k[cb * 16 + l15][lg * 8];
      bf16x8 kf1 = *(const bf16x8*)&lds_k[cb * 16 + l15][32 + lg * 8];
      f32x4 t = {0.f, 0.f, 0.f, 0.f};
      t = __builtin_amdgcn_mfma_f32_16x16x32_bf16(qf0, kf0, t, 0, 0, 0);
      t = __builtin_amdgcn_mfma_f32_16x16x32_bf16(qf1, kf1, t, 0, 0, 0);
      sa[cb] = t;
    }
    __builtin_amdgcn_s_setprio(0);

    const bool diag = (j0 == q0);
    float pv[4][4];
    float tmax[4] = {-1e30f, -1e30f, -1e30f, -1e30f};
    if (!diag && kvm == ~0ull) {
      // fast path: no masking at all
#pragma unroll
      for (int cb = 0; cb < 4; cb++)
#pragma unroll
        for (int r = 0; r < 4; r++) {
          const float s = sa[cb][r];
          pv[cb][r] = s;
          tmax[r] = fmaxf(tmax[r], s);
        }
    } else {
#pragma unroll
      for (int cb = 0; cb < 4; cb++) {
        const int kk = cb * 16 + l15;
        const bool mk = (kvm >> kk) & 1ull;
#pragma unroll
        for (int r = 0; r < 4; r++) {
          float s = sa[cb][r];
          const bool ok = mk && (!diag || (j0 + kk <= qc0 + r));
          s = ok ? s : -1e30f;
          pv[cb][r] = s;
          tmax[r] = fmaxf(tmax[r], s);
        }
      }
    }
#pragma unroll
    for (int r = 0; r < 4; r++) {
      float t = tmax[r];
      t = fmaxf(t, __shfl_xor(t, 1, 16));
      t = fmaxf(t, __shfl_xor(t, 2, 16));
      t = fmaxf(t, __shfl_xor(t, 4, 16));
      t = fmaxf(t, __shfl_xor(t, 8, 16));
      const float mnew = fmaxf(mr[r], t);
      const float sc2 = __builtin_amdgcn_exp2f(mr[r] - mnew);
      mr[r] = mnew;
      float ts = 0.f;
#pragma unroll
      for (int cb = 0; cb < 4; cb++) {
        const float pe = __builtin_amdgcn_exp2f(pv[cb][r] - mnew);
        pv[cb][r] = pe;
        ts += pe;
      }
      ts += __shfl_xor(ts, 1, 16);
      ts += __shfl_xor(ts, 2, 16);
      ts += __shfl_xor(ts, 4, 16);
      ts += __shfl_xor(ts, 8, 16);
      lr[r] = lr[r] * sc2 + ts;
      o[0][r] *= sc2; o[1][r] *= sc2; o[2][r] *= sc2; o[3][r] *= sc2;
    }

    // P -> wave-private LDS, reread as A-fragment
#pragma unroll
    for (int cb = 0; cb < 4; cb++)
#pragma unroll
      for (int r = 0; r < 4; r++)
        lds_p[w][lg * 4 + r][cb * 16 + l15] = f2bf(pv[cb][r]);
    bf16x8 pf0 = *(const bf16x8*)&lds_p[w][l15][lg * 8];
    bf16x8 pf1 = *(const bf16x8*)&lds_p[w][l15][32 + lg * 8];

    __builtin_amdgcn_s_setprio(1);
#pragma unroll
    for (int nb = 0; nb < 4; nb++) {
      bf16x8 vf0 = *(const bf16x8*)&lds_vt[nb * 16 + l15][lg * 8];
      bf16x8 vf1 = *(const bf16x8*)&lds_vt[nb * 16 + l15][32 + lg * 8];
      f32x4 t = o[nb];
      t = __builtin_amdgcn_mfma_f32_16x16x32_bf16(pf0, vf0, t, 0, 0, 0);
      t = __builtin_amdgcn_mfma_f32_16x16x32_bf16(pf1, vf1, t, 0, 0, 0);
      o[nb] = t;
    }
    __builtin_amdgcn_s_setprio(0);
  }

  const long zbase = (long)(b * DM + h * DH) * T_SZ;
  float inv[4];
#pragma unroll
  for (int r = 0; r < 4; r++) inv[r] = (lr[r] > 0.f) ? (1.f / lr[r]) : 0.f;
#pragma unroll
  for (int nb = 0; nb < 4; nb++) {
    u16x4 pk;
#pragma unroll
    for (int r = 0; r < 4; r++) pk[r] = f2bf(o[nb][r] * inv[r]);
    *(u16x4*)&Zt[zbase + (long)(nb * 16 + l15) * T_SZ + qc0] = pk;
  }
}

extern "C" void kernel_launch(void* const* d_in, const int* in_sizes, int n_in,
                              void* d_out, int out_size, void* d_ws, size_t ws_size,
                              hipStream_t stream) {
  const float* q_raw  = (const float*)d_in[0];
  const float* kv_raw = (const float*)d_in[1];
  const int*   kmask  = (const int*)d_in[2];
  const float* Wq = (const float*)d_in[3];
  const float* Wk = (const float*)d_in[4];
  const float* Wv = (const float*)d_in[5];
  const float* Wo = (const float*)d_in[6];
  float* out = (float*)d_out;

  // 1/sqrt(64) * log2(e): softmax runs in exp2 domain
  const float QSCALE = 0.125f * 1.44269504088896f;

  unsigned short* ws = (unsigned short*)d_ws;
  unsigned short* Qh = ws;                     // [32][2048][64] bf16  8 MB
  unsigned short* Kh = ws + 4194304;           //                      8 MB
  unsigned short* Vt = ws + 8388608;           // [2][1024][2048]      8 MB
  unsigned short* Zt = ws + 12582912;          // [2][1024][2048]      8 MB
  const bool full = ws_size >= (size_t)58720256;

  if (full) {
    unsigned short* wqb = ws + 16777216;
    unsigned short* wkb = ws + 17825792;
    unsigned short* wvb = ws + 18874368;
    unsigned short* wob = ws + 19922944;
    unsigned short* qb  = ws + 20971520;
    unsigned short* kvb = ws + 25165824;
    cvt_w4<<<dim3(256, 4), 256, 0, stream>>>(Wq, Wk, Wv, Wo, wqb, wkb, wvb, wob, QSCALE);
    cvt_in2<<<dim3(1024, 2), 256, 0, stream>>>(q_raw, kv_raw, qb, kvb);
    gemm2<1, 1, 0><<<dim3(16, 32, 2), 256, 0, stream>>>(
        qb, kvb, DM, wqb, wkb, DM, 0L, Qh, Kh, DM);
    gemm2<1, 1, 2><<<dim3(32, 8, 2), 256, 0, stream>>>(
        wvb, nullptr, DM, kvb, nullptr, DM, 2097152L, Vt, nullptr, DM);
    attn_kernel<<<dim3(1024), 256, 0, stream>>>(Qh, Kh, Vt, kmask, Zt);
    gemm2<1, 1, 1><<<dim3(16, 8, 4), 256, 0, stream>>>(
        Zt, nullptr, T_SZ, wob, nullptr, DM, 0L, out, nullptr, DM);
  } else {
    // conservative path: fits in proven 33.5 MB (weights alias Zt region)
    unsigned short* wqb = ws + 12582912;
    unsigned short* wkb = ws + 13631488;
    unsigned short* wvb = ws + 14680064;
    unsigned short* wob = wqb;  // placeholder, unused in this path
    (void)wob;
    cvt_w4<<<dim3(256, 3), 256, 0, stream>>>(Wq, Wk, Wv, Wv, wqb, wkb, wvb, wvb, QSCALE);
    gemm2<0, 1, 0><<<dim3(16, 32, 2), 256, 0, stream>>>(
        q_raw, kv_raw, DM, wqb, wkb, DM, 0L, Qh, Kh, DM);
    gemm2<1, 0, 2><<<dim3(32, 8, 2), 256, 0, stream>>>(
        wvb, nullptr, DM, kv_raw, nullptr, DM, 2097152L, Vt, nullptr, DM);
    attn_kernel<<<dim3(1024), 256, 0, stream>>>(Qh, Kh, Vt, kmask, Zt);
    gemm2<1, 0, 1><<<dim3(16, 8, 4), 256, 0, stream>>>(
        Zt, nullptr, T_SZ, Wo, nullptr, DM, 0L, out, nullptr, DM);
  }
}

// Round 6
// 141.290 us; speedup vs baseline: 1.2643x; 1.2643x over previous
//
#include <hip/hip_runtime.h>

#define B_SZ 2
#define T_SZ 2048
#define DM   1024
#define NH   16
#define DH   64

typedef __attribute__((ext_vector_type(8))) short bf16x8;
typedef __attribute__((ext_vector_type(4))) float f32x4;
typedef __attribute__((ext_vector_type(4))) unsigned int u32x4;
typedef __attribute__((ext_vector_type(4))) unsigned short u16x4;

__device__ __forceinline__ unsigned short f2bf(float f) {
  unsigned u = __builtin_bit_cast(unsigned, f);
  u += 0x7FFFu + ((u >> 16) & 1u);
  return (unsigned short)(u >> 16);
}
__device__ __forceinline__ unsigned packbf(float lo, float hi) {
  return (unsigned)f2bf(lo) | ((unsigned)f2bf(hi) << 16);
}

// DPP cross-lane (within 16-lane row), pure VALU — no LDS round-trip
template<int CTRL>
__device__ __forceinline__ float dpp_mov(float x) {
  return __builtin_bit_cast(float,
      __builtin_amdgcn_update_dpp(0, __builtin_bit_cast(int, x), CTRL, 0xF, 0xF, true));
}
__device__ __forceinline__ float rowmax16(float x) {
  x = fmaxf(x, dpp_mov<0x128>(x));  // row_ror:8
  x = fmaxf(x, dpp_mov<0x124>(x));  // row_ror:4
  x = fmaxf(x, dpp_mov<0x122>(x));  // row_ror:2
  x = fmaxf(x, dpp_mov<0x121>(x));  // row_ror:1
  return x;
}
__device__ __forceinline__ float rowsum16(float x) {
  x += dpp_mov<0x128>(x);
  x += dpp_mov<0x124>(x);
  x += dpp_mov<0x122>(x);
  x += dpp_mov<0x121>(x);
  return x;
}

// stage 16 f32 -> 16 bf16 into LDS
__device__ __forceinline__ void stage16(const float* src, unsigned short* dst) {
  const f32x4* ps = (const f32x4*)src;
  f32x4 v0 = ps[0], v1 = ps[1], v2 = ps[2], v3 = ps[3];
  u32x4 w0, w1;
  w0[0] = packbf(v0[0], v0[1]); w0[1] = packbf(v0[2], v0[3]);
  w0[2] = packbf(v1[0], v1[1]); w0[3] = packbf(v1[2], v1[3]);
  w1[0] = packbf(v2[0], v2[1]); w1[1] = packbf(v2[2], v2[3]);
  w1[2] = packbf(v3[0], v3[1]); w1[3] = packbf(v3[2], v3[3]);
  *(u32x4*)dst = w0;
  *(u32x4*)(dst + 8) = w1;
}

// async global->LDS, 16B per lane
__device__ __forceinline__ void gload16(const unsigned short* g, unsigned short* l) {
  __builtin_amdgcn_global_load_lds(
      (const __attribute__((address_space(1))) unsigned int*)(const void*)g,
      (__attribute__((address_space(3))) unsigned int*)(void*)l, 16, 0, 0);
}

__device__ __forceinline__ void cvt16(const float* s, unsigned short* d, float scale) {
  const f32x4* ps = (const f32x4*)s;
  f32x4 v0 = ps[0] * scale, v1 = ps[1] * scale, v2 = ps[2] * scale, v3 = ps[3] * scale;
  u32x4 w0, w1;
  w0[0] = packbf(v0[0], v0[1]); w0[1] = packbf(v0[2], v0[3]);
  w0[2] = packbf(v1[0], v1[1]); w0[3] = packbf(v1[2], v1[3]);
  w1[0] = packbf(v2[0], v2[1]); w1[1] = packbf(v2[2], v2[3]);
  w1[2] = packbf(v3[0], v3[1]); w1[3] = packbf(v3[2], v3[3]);
  *(u32x4*)d = w0;
  *(u32x4*)(d + 8) = w1;
}

__global__ __launch_bounds__(256) void cvt_w4(
    const float* __restrict__ s0, const float* __restrict__ s1,
    const float* __restrict__ s2, const float* __restrict__ s3,
    unsigned short* __restrict__ d0, unsigned short* __restrict__ d1,
    unsigned short* __restrict__ d2, unsigned short* __restrict__ d3,
    float qscale) {
  const int y = blockIdx.y;
  const float* s = (y == 0) ? s0 : (y == 1) ? s1 : (y == 2) ? s2 : s3;
  unsigned short* d = (y == 0) ? d0 : (y == 1) ? d1 : (y == 2) ? d2 : d3;
  const float sc = (y == 0) ? qscale : 1.0f;
  const int i = (blockIdx.x * 256 + threadIdx.x) * 16;
  cvt16(s + i, d + i, sc);
}

__global__ __launch_bounds__(256) void cvt_in2(
    const float* __restrict__ s0, const float* __restrict__ s1,
    unsigned short* __restrict__ d0, unsigned short* __restrict__ d1) {
  const int y = blockIdx.y;
  const float* s = y ? s1 : s0;
  unsigned short* d = y ? d1 : d0;
  const int i = (blockIdx.x * 256 + threadIdx.x) * 16;
  cvt16(s + i, d + i, 1.0f);
}

// C = A * B^T, tile 128x64, BK=32, MFMA 16x16x32 bf16.
// Flat grid + XCD-chunked swizzle: chunk of gridDim/8 consecutive (n-fastest)
// blocks lands on one XCD so A/B panels stay L2-resident.
template<int AMODE, int BMODE, int CMODE>
__global__ __launch_bounds__(256) void gemm2(
    const void* __restrict__ A0, const void* __restrict__ A1, int lda,
    const void* __restrict__ B0, const void* __restrict__ B1, int ldb, long bZ,
    void* __restrict__ C0, void* __restrict__ C1, int K, int nx, int ny) {
  __shared__ unsigned short As[128 * 32];
  __shared__ unsigned short Bs[64 * 32];
  const int tid = threadIdx.x, lane = tid & 63, w = tid >> 6;
  const int wm = w >> 1, wn = w & 1;
  const int l15 = lane & 15, lg = lane >> 4;

  const int cpx = gridDim.x >> 3;
  const int flat = (blockIdx.x & 7) * cpx + (blockIdx.x >> 3);
  const int nbk = flat % nx;
  const int rest = flat / nx;
  const int mbk = rest % ny;
  const int z = rest / ny;
  const int mblk = mbk * 128, nblk = nbk * 64;

  const void* Ap; const void* Bp; void* Cp;
  long aoff = 0; int zb = 0, zs = 0;
  if constexpr (CMODE == 0) {
    Ap = z ? A1 : A0; Bp = z ? B1 : B0; Cp = z ? C1 : C0;
  } else if constexpr (CMODE == 2) {
    Ap = A0; Cp = C0;
    if constexpr (BMODE == 1) Bp = (const void*)((const unsigned short*)B0 + (long)z * bZ);
    else                      Bp = (const void*)((const float*)B0 + (long)z * bZ);
  } else {
    Ap = A0; Bp = B0; Cp = C0;
    zb = z >> 1; zs = z & 1;
    aoff = (long)zb * 2097152 + (long)zs * 1024;
  }

  f32x4 acc[4][2];
#pragma unroll
  for (int i = 0; i < 4; i++)
#pragma unroll
    for (int j = 0; j < 2; j++) acc[i][j] = (f32x4){0.f, 0.f, 0.f, 0.f};

  const int asr = tid >> 1, asc = (tid & 1) * 16;
  const int agr = w * 32 + (lane >> 2), agc = (lane & 3) * 8;
  const int bgr = w * 16 + (lane >> 2), bgc = (lane & 3) * 8;

  for (int k0 = 0; k0 < K; k0 += 32) {
    if constexpr (AMODE == 0) {
      stage16((const float*)Ap + (long)(mblk + asr) * lda + k0 + asc, &As[asr * 32 + asc]);
    } else {
      const unsigned short* Ab = (const unsigned short*)Ap + aoff;
      gload16(Ab + (long)(mblk + agr) * lda + k0 + agc, &As[w * 1024]);
      gload16(Ab + (long)(mblk + agr + 16) * lda + k0 + agc, &As[w * 1024 + 512]);
    }
    if constexpr (BMODE == 0) {
      if (tid < 128)
        stage16((const float*)Bp + (long)(nblk + asr) * ldb + k0 + asc, &Bs[asr * 32 + asc]);
    } else {
      gload16((const unsigned short*)Bp + (long)(nblk + bgr) * ldb + k0 + bgc, &Bs[w * 512]);
    }
    __syncthreads();

    bf16x8 af[4], bfr[2];
#pragma unroll
    for (int mi = 0; mi < 4; mi++)
      af[mi] = *(const bf16x8*)&As[(wm * 64 + mi * 16 + l15) * 32 + lg * 8];
#pragma unroll
    for (int nj = 0; nj < 2; nj++)
      bfr[nj] = *(const bf16x8*)&Bs[(wn * 32 + nj * 16 + l15) * 32 + lg * 8];
#pragma unroll
    for (int mi = 0; mi < 4; mi++)
#pragma unroll
      for (int nj = 0; nj < 2; nj++)
        acc[mi][nj] = __builtin_amdgcn_mfma_f32_16x16x32_bf16(af[mi], bfr[nj], acc[mi][nj], 0, 0, 0);
    __syncthreads();
  }

#pragma unroll
  for (int mi = 0; mi < 4; mi++) {
#pragma unroll
    for (int nj = 0; nj < 2; nj++) {
#pragma unroll
      for (int r = 0; r < 4; r++) {
        const int i = mblk + wm * 64 + mi * 16 + lg * 4 + r;
        const int n = nblk + wn * 32 + nj * 16 + l15;
        const float v = acc[mi][nj][r];
        if constexpr (CMODE == 0) {
          const int b = i >> 11, t = i & 2047, h = n >> 6, d = n & 63;
          ((unsigned short*)Cp)[((long)(b * NH + h) * T_SZ + t) * DH + d] = f2bf(v);
        } else if constexpr (CMODE == 2) {
          ((unsigned short*)Cp)[(long)z * 2097152 + (long)i * 2048 + n] = f2bf(v);
        } else {
          ((float*)Cp)[(long)zb * T_SZ * DM + (long)(2 * i + zs) * DM + n] = v;
        }
      }
    }
  }
}

// Flash attention, causal + kv padding mask.
// 8-wave blocks over paired q-tiles (p, 31-p): waves 0-3 own segment a
// (q0a, large), waves 4-7 own segment b (q0b, small). Staging shared.
// Qh/Kh: [b*16+h][t][d] bf16 (Q pre-scaled log2e/8). Vt/Zt: [b][c][t] bf16.
__global__ __launch_bounds__(512) void attn_kernel(const unsigned short* __restrict__ Qh,
                                                   const unsigned short* __restrict__ Kh,
                                                   const unsigned short* __restrict__ Vt,
                                                   const int* __restrict__ kmask,
                                                   unsigned short* __restrict__ Zt) {
  __shared__ unsigned short lds_k[64][72];
  __shared__ unsigned short lds_vt[64][72];
  __shared__ unsigned short lds_p[8][16][72];
  const int tid = threadIdx.x, lane = tid & 63, w = tid >> 6;
  const int l15 = lane & 15, lg = lane >> 4;
  // XCD-aware decode: 4 bh per XCD (K/V L2-resident per XCD)
  const int wg = blockIdx.x;
  const int xcd = wg & 7, lin = wg >> 3;       // lin in 0..63
  const int bh = xcd * 4 + (lin >> 4);
  const int p = lin & 15;
  const int b = bh >> 4, h = bh & 15;
  const int q0a = (31 - p) * 64;
  const int q0b = p * 64;
  const int q0 = (w < 4) ? q0a : q0b;          // this wave's segment
  const unsigned short* Qb = Qh + ((long)bh << 17);
  const unsigned short* Kb = Kh + ((long)bh << 17);
  const unsigned short* Vtb = Vt + ((long)(b * DM + h * DH)) * T_SZ;

  const int qra = q0 + (w & 3) * 16 + l15;
  bf16x8 qf0 = *(const bf16x8*)(Qb + ((long)qra << 6) + lg * 8);
  bf16x8 qf1 = *(const bf16x8*)(Qb + ((long)qra << 6) + 32 + lg * 8);

  f32x4 o[4];
  float mr[4], lr[4];
#pragma unroll
  for (int i = 0; i < 4; i++) {
    o[i] = (f32x4){0.f, 0.f, 0.f, 0.f};
    mr[i] = -1e30f; lr[i] = 0.f;
  }

  // staging: threads 0-255 stage K tile, 256-511 stage Vt tile (32B each)
  const int half = tid >> 8;
  const int sr = (tid & 255) >> 2, sc = (tid & 3) * 16;
  const unsigned short* kp = Kb + ((long)sr << 6) + sc;
  const unsigned short* vp = Vtb + (long)sr * T_SZ + sc;
  const int mbase = b * T_SZ + lane;
  const int qc0 = q0 + (w & 3) * 16 + lg * 4;

  u32x4 r0, r1;
  int rmk;
  auto issue = [&](int j0) {
    const u32x4* s = (const u32x4*)(half ? (vp + j0) : (kp + ((long)j0 << 6)));
    r0 = s[0]; r1 = s[1];
    rmk = kmask[mbase + j0];
  };

  issue(0);
  for (int j0 = 0; j0 <= q0a; j0 += 64) {
    __syncthreads();
    if (half) { *(u32x4*)&lds_vt[sr][sc] = r0; *(u32x4*)&lds_vt[sr][sc + 8] = r1; }
    else      { *(u32x4*)&lds_k[sr][sc]  = r0; *(u32x4*)&lds_k[sr][sc + 8]  = r1; }
    const unsigned long long kvm = __ballot(rmk != 0);
    __syncthreads();
    if (j0 + 64 <= q0a) issue(j0 + 64);

    if (w < 4 || j0 <= q0b) {
      // S = Q K^T (scores in log2 domain via Q pre-scale)
      f32x4 sa[4];
      __builtin_amdgcn_s_setprio(1);
#pragma unroll
      for (int cb = 0; cb < 4; cb++) {
        bf16x8 kf0 = *(const bf16x8*)&lds_k[cb * 16 + l15][lg * 8];
        bf16x8 kf1 = *(const bf16x8*)&lds_k[cb * 16 + l15][32 + lg * 8];
        f32x4 t = {0.f, 0.f, 0.f, 0.f};
        t = __builtin_amdgcn_mfma_f32_16x16x32_bf16(qf0, kf0, t, 0, 0, 0);
        t = __builtin_amdgcn_mfma_f32_16x16x32_bf16(qf1, kf1, t, 0, 0, 0);
        sa[cb] = t;
      }
      __builtin_amdgcn_s_setprio(0);

      const bool diag = (j0 == q0);
      float pv[4][4];
      float tmax[4] = {-1e30f, -1e30f, -1e30f, -1e30f};
      if (!diag && kvm == ~0ull) {
#pragma unroll
        for (int cb = 0; cb < 4; cb++)
#pragma unroll
          for (int r = 0; r < 4; r++) {
            const float s = sa[cb][r];
            pv[cb][r] = s;
            tmax[r] = fmaxf(tmax[r], s);
          }
      } else {
#pragma unroll
        for (int cb = 0; cb < 4; cb++) {
          const int kk = cb * 16 + l15;
          const bool mk = (kvm >> kk) & 1ull;
#pragma unroll
          for (int r = 0; r < 4; r++) {
            float s = sa[cb][r];
            const bool ok = mk && (!diag || (j0 + kk <= qc0 + r));
            s = ok ? s : -1e30f;
            pv[cb][r] = s;
            tmax[r] = fmaxf(tmax[r], s);
          }
        }
      }
#pragma unroll
      for (int r = 0; r < 4; r++) {
        const float t = rowmax16(tmax[r]);
        const float mnew = fmaxf(mr[r], t);
        const float sc2 = __builtin_amdgcn_exp2f(mr[r] - mnew);
        mr[r] = mnew;
        float ts = 0.f;
#pragma unroll
        for (int cb = 0; cb < 4; cb++) {
          const float pe = __builtin_amdgcn_exp2f(pv[cb][r] - mnew);
          pv[cb][r] = pe;
          ts += pe;
        }
        ts = rowsum16(ts);
        lr[r] = lr[r] * sc2 + ts;
        o[0][r] *= sc2; o[1][r] *= sc2; o[2][r] *= sc2; o[3][r] *= sc2;
      }

      // P -> wave-private LDS, reread as A-fragment
#pragma unroll
      for (int cb = 0; cb < 4; cb++)
#pragma unroll
        for (int r = 0; r < 4; r++)
          lds_p[w][lg * 4 + r][cb * 16 + l15] = f2bf(pv[cb][r]);
      bf16x8 pf0 = *(const bf16x8*)&lds_p[w][l15][lg * 8];
      bf16x8 pf1 = *(const bf16x8*)&lds_p[w][l15][32 + lg * 8];

      __builtin_amdgcn_s_setprio(1);
#pragma unroll
      for (int nb = 0; nb < 4; nb++) {
        bf16x8 vf0 = *(const bf16x8*)&lds_vt[nb * 16 + l15][lg * 8];
        bf16x8 vf1 = *(const bf16x8*)&lds_vt[nb * 16 + l15][32 + lg * 8];
        f32x4 t = o[nb];
        t = __builtin_amdgcn_mfma_f32_16x16x32_bf16(pf0, vf0, t, 0, 0, 0);
        t = __builtin_amdgcn_mfma_f32_16x16x32_bf16(pf1, vf1, t, 0, 0, 0);
        o[nb] = t;
      }
      __builtin_amdgcn_s_setprio(0);
    }
  }

  const long zbase = (long)(b * DM + h * DH) * T_SZ;
  float inv[4];
#pragma unroll
  for (int r = 0; r < 4; r++) inv[r] = (lr[r] > 0.f) ? (1.f / lr[r]) : 0.f;
#pragma unroll
  for (int nb = 0; nb < 4; nb++) {
    u16x4 pk;
#pragma unroll
    for (int r = 0; r < 4; r++) pk[r] = f2bf(o[nb][r] * inv[r]);
    *(u16x4*)&Zt[zbase + (long)(nb * 16 + l15) * T_SZ + qc0] = pk;
  }
}

extern "C" void kernel_launch(void* const* d_in, const int* in_sizes, int n_in,
                              void* d_out, int out_size, void* d_ws, size_t ws_size,
                              hipStream_t stream) {
  const float* q_raw  = (const float*)d_in[0];
  const float* kv_raw = (const float*)d_in[1];
  const int*   kmask  = (const int*)d_in[2];
  const float* Wq = (const float*)d_in[3];
  const float* Wk = (const float*)d_in[4];
  const float* Wv = (const float*)d_in[5];
  const float* Wo = (const float*)d_in[6];
  float* out = (float*)d_out;

  // 1/sqrt(64) * log2(e): softmax runs in exp2 domain
  const float QSCALE = 0.125f * 1.44269504088896f;

  unsigned short* ws = (unsigned short*)d_ws;
  unsigned short* Qh = ws;                     // [32][2048][64] bf16  8 MB
  unsigned short* Kh = ws + 4194304;           //                      8 MB
  unsigned short* Vt = ws + 8388608;           // [2][1024][2048]      8 MB
  unsigned short* Zt = ws + 12582912;          // [2][1024][2048]      8 MB
  const bool full = ws_size >= (size_t)58720256;

  if (full) {
    unsigned short* wqb = ws + 16777216;
    unsigned short* wkb = ws + 17825792;
    unsigned short* wvb = ws + 18874368;
    unsigned short* wob = ws + 19922944;
    unsigned short* qb  = ws + 20971520;
    unsigned short* kvb = ws + 25165824;
    cvt_w4<<<dim3(256, 4), 256, 0, stream>>>(Wq, Wk, Wv, Wo, wqb, wkb, wvb, wob, QSCALE);
    cvt_in2<<<dim3(1024, 2), 256, 0, stream>>>(q_raw, kv_raw, qb, kvb);
    gemm2<1, 1, 0><<<dim3(1024), 256, 0, stream>>>(
        qb, kvb, DM, wqb, wkb, DM, 0L, Qh, Kh, DM, 16, 32);
    gemm2<1, 1, 2><<<dim3(512), 256, 0, stream>>>(
        wvb, nullptr, DM, kvb, nullptr, DM, 2097152L, Vt, nullptr, DM, 32, 8);
    attn_kernel<<<dim3(512), 512, 0, stream>>>(Qh, Kh, Vt, kmask, Zt);
    gemm2<1, 1, 1><<<dim3(512), 256, 0, stream>>>(
        Zt, nullptr, T_SZ, wob, nullptr, DM, 0L, out, nullptr, DM, 16, 8);
  } else {
    // conservative path: fits in proven 33.5 MB (weights alias Zt region)
    unsigned short* wqb = ws + 12582912;
    unsigned short* wkb = ws + 13631488;
    unsigned short* wvb = ws + 14680064;
    cvt_w4<<<dim3(256, 3), 256, 0, stream>>>(Wq, Wk, Wv, Wv, wqb, wkb, wvb, wvb, QSCALE);
    gemm2<0, 1, 0><<<dim3(1024), 256, 0, stream>>>(
        q_raw, kv_raw, DM, wqb, wkb, DM, 0L, Qh, Kh, DM, 16, 32);
    gemm2<1, 0, 2><<<dim3(512), 256, 0, stream>>>(
        wvb, nullptr, DM, kv_raw, nullptr, DM, 2097152L, Vt, nullptr, DM, 32, 8);
    attn_kernel<<<dim3(512), 512, 0, stream>>>(Qh, Kh, Vt, kmask, Zt);
    gemm2<1, 0, 1><<<dim3(512), 256, 0, stream>>>(
        Zt, nullptr, T_SZ, Wo, nullptr, DM, 0L, out, nullptr, DM, 16, 8);
  }
}